// Round 1
// baseline (354.842 us; speedup 1.0000x reference)
//
#include <hip/hip_runtime.h>
#include <hip/hip_bf16.h>
#include <cstdint>

typedef __attribute__((ext_vector_type(4))) float f32x4;
typedef __attribute__((ext_vector_type(8))) short bf16x8;
typedef unsigned short u16;
typedef unsigned int u32;

__device__ __forceinline__ u16 f2b(float x) {
  __hip_bfloat16 h = __float2bfloat16(x);
  return *reinterpret_cast<u16*>(&h);
}

__device__ __forceinline__ void gload16(const void* g, void* l) {
  __builtin_amdgcn_global_load_lds((const __attribute__((address_space(1))) u32*)g,
                                   (__attribute__((address_space(3))) u32*)l, 16, 0, 0);
}

// ---------------- converts ----------------

__global__ void cvt_f32_bf16(const float* __restrict__ in, u16* __restrict__ out, int n4) {
  int idx = (blockIdx.x * 256 + threadIdx.x);
  if (idx < n4) {
    const float4 v = *(const float4*)(in + (size_t)idx * 4);
    u16* o = out + (size_t)idx * 4;
    o[0] = f2b(v.x); o[1] = f2b(v.y); o[2] = f2b(v.z); o[3] = f2b(v.w);
  }
}

// out[n][k] = in[k][n] as bf16.  Three column-partitioned sources.
__global__ void w_transpose_cvt(const float* __restrict__ w0, const float* __restrict__ w1,
                                const float* __restrict__ w2, int b0, int b1,
                                int N0, int N1, int N2,
                                u16* __restrict__ out, int K) {
  __shared__ float tile[32][33];
  int k0 = blockIdx.x * 32, n0 = blockIdx.y * 32;
  const float* src; int srcN; int c0;
  if (n0 < b0)      { src = w0; srcN = N0; c0 = n0; }
  else if (n0 < b1) { src = w1; srcN = N1; c0 = n0 - b0; }
  else              { src = w2; srcN = N2; c0 = n0 - b1; }
  int tx = threadIdx.x & 31, ty = threadIdx.x >> 5;
#pragma unroll
  for (int j = 0; j < 32; j += 8)
    tile[ty + j][tx] = src[(size_t)(k0 + ty + j) * srcN + c0 + tx];
  __syncthreads();
#pragma unroll
  for (int j = 0; j < 32; j += 8)
    out[(size_t)(n0 + ty + j) * K + k0 + tx] = f2b(tile[tx][ty + j]);
}

__global__ void pack_bias(const float* __restrict__ bq, const float* __restrict__ bk,
                          const float* __restrict__ bv, float* __restrict__ out) {
  int i = blockIdx.x * 256 + threadIdx.x;
  if (i < 3072) out[i] = (i < 2048) ? bq[i] : ((i < 2560) ? bk[i - 2048] : bv[i - 2560]);
}

// V slice of qkv -> transposed bf16 (B*KVH, 128, 2048)
__global__ void v_transpose_cvt(const float* __restrict__ qkv, u16* __restrict__ vt) {
  __shared__ float tile[32][33];
  int s0 = blockIdx.x * 32;
  int d0 = blockIdx.y * 32;
  int z = blockIdx.z;              // b*4 + kvh
  int b = z >> 2, kvh = z & 3;
  int tx = threadIdx.x & 31, ty = threadIdx.x >> 5;
#pragma unroll
  for (int j = 0; j < 32; j += 8)
    tile[ty + j][tx] = qkv[((size_t)(b * 2048 + s0 + ty + j)) * 3072 + 2560 + kvh * 128 + d0 + tx];
  __syncthreads();
#pragma unroll
  for (int j = 0; j < 32; j += 8)
    vt[((size_t)z * 128 + d0 + ty + j) * 2048 + s0 + tx] = f2b(tile[tx][ty + j]);
}

// ---------------- RoPE ----------------
// reads qkv fp32 rows (B*S, 3072); writes ((b*NH+h), s, 128) bf16 with RoPE applied.
__global__ void rope_cvt(const float* __restrict__ qkv, u16* __restrict__ out,
                         int lognh, int col0, float scale) {
  int idx = blockIdx.x * 256 + threadIdx.x;   // pair index
  int i = idx & 63;                            // pair within head
  int nh = 1 << lognh;
  int h = (idx >> 6) & (nh - 1);
  int bs = idx >> (6 + lognh);                 // 0..4095
  int s = bs & 2047;
  int b = bs >> 11;
  const float* src = qkv + (size_t)bs * 3072 + col0 + h * 128 + 2 * i;
  float tr = src[0], ti = src[1];
  float theta = expf(-(float)i * 0.14391156831212787f);  // ln(10000)/64
  float ang = (float)s * theta;
  float sv, cv;
  sincosf(ang, &sv, &cv);
  float orr = (tr * cv - ti * sv) * scale;
  float oii = (tr * sv + ti * cv) * scale;
  u16* dst = out + (((size_t)(b * nh + h) * 2048 + s) * 128 + 2 * i);
  dst[0] = f2b(orr);
  dst[1] = f2b(oii);
}

// ---------------- GEMM (m97 structure): C = A @ Bt^T + bias ----------------
// A: M x K bf16 row-major; Bt: N x K bf16 row-major; C: M x N fp32.
__global__ __launch_bounds__(256) void gemm_bt_bf16(
    const u16* __restrict__ A, const u16* __restrict__ Bt,
    const float* __restrict__ bias, float* __restrict__ C,
    int M, int N, int K) {
  __shared__ u16 As[128 * 32];
  __shared__ u16 Bs[128 * 32];
  const int tid = threadIdx.x;
  const int lane = tid & 63;
  const int w = tid >> 6;
  const int wr = w >> 1, wc = w & 1;
  const int m0 = blockIdx.y * 128;
  const int n0 = blockIdx.x * 128;

  f32x4 acc[4][4] = {};

  for (int k0 = 0; k0 < K; k0 += 32) {
#pragma unroll
    for (int it = 0; it < 2; ++it) {
      int c = tid + it * 256;
      int row = c >> 2;
      int off = (c & 3) * 8;
      gload16(A + (size_t)(m0 + row) * K + k0 + off, (u16*)As + w * 512 + it * 2048);
      gload16(Bt + (size_t)(n0 + row) * K + k0 + off, (u16*)Bs + w * 512 + it * 2048);
    }
    __syncthreads();
    const int col8 = (lane >> 4) * 8;
    bf16x8 a[4], bfr[4];
#pragma unroll
    for (int m = 0; m < 4; ++m)
      a[m] = *(const bf16x8*)&As[(wr * 64 + m * 16 + (lane & 15)) * 32 + col8];
#pragma unroll
    for (int n = 0; n < 4; ++n)
      bfr[n] = *(const bf16x8*)&Bs[(wc * 64 + n * 16 + (lane & 15)) * 32 + col8];
#pragma unroll
    for (int m = 0; m < 4; ++m)
#pragma unroll
      for (int n = 0; n < 4; ++n)
        acc[m][n] = __builtin_amdgcn_mfma_f32_16x16x32_bf16(a[m], bfr[n], acc[m][n], 0, 0, 0);
    __syncthreads();
  }

#pragma unroll
  for (int m = 0; m < 4; ++m) {
    int row = m0 + wr * 64 + m * 16 + ((lane >> 4) << 2);
#pragma unroll
    for (int n = 0; n < 4; ++n) {
      int col = n0 + wc * 64 + n * 16 + (lane & 15);
      float bvv = bias ? bias[col] : 0.f;
      float* cp = C + (size_t)row * N + col;
#pragma unroll
      for (int r = 0; r < 4; ++r) cp[(size_t)r * N] = acc[m][n][r] + bvv;
    }
  }
}

// ---------------- flash attention ----------------
// Qr: (B*H, 2048, 128) bf16, pre-scaled by 1/sqrt(128).
// Kr: (B*KVH, 2048, 128) bf16.  Vt: (B*KVH, 128, 2048) bf16.
// Att out: (B*2048, 2048) bf16 (b, s, h*128+d).
__global__ __launch_bounds__(256) void flash_attn(
    const u16* __restrict__ Qr, const u16* __restrict__ Kr,
    const u16* __restrict__ Vt, u16* __restrict__ Att) {
  __shared__ u16 Ks[64 * 128];
  __shared__ u16 Vs[128 * 64];
  __shared__ u16 Ps[4 * 16 * 72];
  const int tid = threadIdx.x, lane = tid & 63, w = tid >> 6;
  const int q0 = blockIdx.x * 64;
  const int h = blockIdx.y;
  const int b = blockIdx.z;
  const int kvh = h >> 2;

  const size_t qbase = ((size_t)(b * 16 + h) * 2048 + q0 + w * 16 + (lane & 15)) * 128 + ((lane >> 4) * 8);
  bf16x8 aq[4];
#pragma unroll
  for (int ks = 0; ks < 4; ++ks) aq[ks] = *(const bf16x8*)&Qr[qbase + ks * 32];

  float m_run[4], l_run[4];
  f32x4 o[8] = {};
#pragma unroll
  for (int r = 0; r < 4; ++r) { m_run[r] = -3.0e38f; l_run[r] = 0.f; }

  const u16* Khead = Kr + (size_t)(b * 4 + kvh) * 2048 * 128;
  const u16* Vhead = Vt + (size_t)(b * 4 + kvh) * 128 * 2048;

  for (int t = 0; t < 32; ++t) {
    // stage K tile (64x128) and V^T tile (128x64), XOR-swizzled via source
#pragma unroll
    for (int it = 0; it < 4; ++it) {
      int c = tid + it * 256;
      int krow = c >> 4;
      int koff = (c & 15) * 16;
      int ksw = koff ^ ((krow & 7) << 4);
      gload16((const char*)(Khead + (size_t)(t * 64 + krow) * 128) + ksw,
              (u16*)Ks + w * 512 + it * 2048);
      int vrow = c >> 3;
      int voff = (c & 7) * 16;
      int vsw = voff ^ ((vrow & 7) << 4);
      gload16((const char*)(Vhead + (size_t)vrow * 2048 + t * 64) + vsw,
              (u16*)Vs + w * 512 + it * 2048);
    }
    __syncthreads();

    // QK^T : per wave 16 q-rows x 64 keys
    f32x4 sfr[4] = {};
#pragma unroll
    for (int n = 0; n < 4; ++n) {
      int row = n * 16 + (lane & 15);
      int rb = row * 256;
#pragma unroll
      for (int ks = 0; ks < 4; ++ks) {
        int off = (ks * 64 + (lane >> 4) * 16) ^ ((row & 7) << 4);
        bf16x8 bk = *(const bf16x8*)((const char*)Ks + rb + off);
        sfr[n] = __builtin_amdgcn_mfma_f32_16x16x32_bf16(aq[ks], bk, sfr[n], 0, 0, 0);
      }
    }

    // online softmax (fp32)
    float scl[4];
#pragma unroll
    for (int r = 0; r < 4; ++r) {
      float mt = fmaxf(fmaxf(sfr[0][r], sfr[1][r]), fmaxf(sfr[2][r], sfr[3][r]));
#pragma unroll
      for (int d = 1; d < 16; d <<= 1) mt = fmaxf(mt, __shfl_xor(mt, d, 64));
      float mn = fmaxf(m_run[r], mt);
      float rs = __expf(m_run[r] - mn);
      float psum = 0.f;
#pragma unroll
      for (int n = 0; n < 4; ++n) {
        float p = __expf(sfr[n][r] - mn);
        sfr[n][r] = p;
        psum += p;
      }
#pragma unroll
      for (int d = 1; d < 16; d <<= 1) psum += __shfl_xor(psum, d, 64);
      l_run[r] = l_run[r] * rs + psum;
      m_run[r] = mn;
      scl[r] = rs;
    }
#pragma unroll
    for (int n2 = 0; n2 < 8; ++n2)
#pragma unroll
      for (int r = 0; r < 4; ++r) o[n2][r] *= scl[r];

    // P -> LDS (bf16), padded stride 72
    {
      int pb = w * 1152;
#pragma unroll
      for (int n = 0; n < 4; ++n)
#pragma unroll
        for (int r = 0; r < 4; ++r)
          Ps[pb + ((lane >> 4) * 4 + r) * 72 + n * 16 + (lane & 15)] = f2b(sfr[n][r]);
    }
    bf16x8 pa[2];
#pragma unroll
    for (int ks = 0; ks < 2; ++ks)
      pa[ks] = *(const bf16x8*)&Ps[w * 1152 + (lane & 15) * 72 + ks * 32 + (lane >> 4) * 8];

    // PV : out 16 x 128
#pragma unroll
    for (int n2 = 0; n2 < 8; ++n2) {
      int row = n2 * 16 + (lane & 15);
      int rb = row * 128;
#pragma unroll
      for (int ks = 0; ks < 2; ++ks) {
        int off = (ks * 64 + (lane >> 4) * 16) ^ ((row & 7) << 4);
        bf16x8 vb = *(const bf16x8*)((const char*)Vs + rb + off);
        o[n2] = __builtin_amdgcn_mfma_f32_16x16x32_bf16(pa[ks], vb, o[n2], 0, 0, 0);
      }
    }
    __syncthreads();
  }

  float inv[4];
#pragma unroll
  for (int r = 0; r < 4; ++r) inv[r] = 1.f / l_run[r];
  size_t orow = (size_t)(b * 2048 + q0 + w * 16 + ((lane >> 4) << 2));
#pragma unroll
  for (int n2 = 0; n2 < 8; ++n2) {
    int col = h * 128 + n2 * 16 + (lane & 15);
#pragma unroll
    for (int r = 0; r < 4; ++r)
      Att[(orow + r) * 2048 + col] = f2b(o[n2][r] * inv[r]);
  }
}

// ---------------- launch ----------------

extern "C" void kernel_launch(void* const* d_in, const int* in_sizes, int n_in,
                              void* d_out, int out_size, void* d_ws, size_t ws_size,
                              hipStream_t stream) {
  const float* x  = (const float*)d_in[0];
  const float* wq = (const float*)d_in[1];
  const float* bq = (const float*)d_in[2];
  const float* wk = (const float*)d_in[3];
  const float* bk = (const float*)d_in[4];
  const float* wv = (const float*)d_in[5];
  const float* bv = (const float*)d_in[6];
  const float* wo = (const float*)d_in[7];
  float* out = (float*)d_out;
  char* ws = (char*)d_ws;

  // workspace layout (bytes); att aliases x_bf (dead after QKV GEMM)
  u16*   x_bf   = (u16*)  (ws + 0);            // 16,777,216
  u16*   att    = (u16*)  (ws + 0);            // reuse after gemm1
  u16*   wqkv_t = (u16*)  (ws + 16777216);     // 12,582,912
  u16*   wo_t   = (u16*)  (ws + 29360128);     //  8,388,608
  float* biasq  = (float*)(ws + 37748736);     //     12,288
  float* qkv    = (float*)(ws + 37761024);     // 50,331,648
  u16*   q_r    = (u16*)  (ws + 88092672);     // 16,777,216
  u16*   k_r    = (u16*)  (ws + 104869888);    //  4,194,304
  u16*   v_t    = (u16*)  (ws + 109064192);    //  4,194,304  (end 113,258,496)

  // 1. converts
  cvt_f32_bf16<<<8192, 256, 0, stream>>>(x, x_bf, 2097152);
  w_transpose_cvt<<<dim3(64, 96), 256, 0, stream>>>(wq, wk, wv, 2048, 2560,
                                                    2048, 512, 512, wqkv_t, 2048);
  w_transpose_cvt<<<dim3(64, 64), 256, 0, stream>>>(wo, wo, wo, 2048, 2560,
                                                    2048, 2048, 2048, wo_t, 2048);
  pack_bias<<<12, 256, 0, stream>>>(bq, bk, bv, biasq);

  // 2. QKV projection: (4096 x 2048) @ (2048 x 3072) + bias -> fp32
  gemm_bt_bf16<<<dim3(24, 32), 256, 0, stream>>>(x_bf, wqkv_t, biasq, qkv, 4096, 3072, 2048);

  // 3. RoPE + layout (scale folded into Q); V transpose
  rope_cvt<<<16384, 256, 0, stream>>>(qkv, q_r, 4, 0, 0.08838834764831845f);
  rope_cvt<<<4096, 256, 0, stream>>>(qkv, k_r, 2, 2048, 1.0f);
  v_transpose_cvt<<<dim3(64, 4, 8), 256, 0, stream>>>(qkv, v_t);

  // 4. flash attention -> att bf16
  flash_attn<<<dim3(32, 16, 2), 256, 0, stream>>>(q_r, k_r, v_t, att);

  // 5. out projection: (4096 x 2048) @ (2048 x 2048) -> d_out fp32
  gemm_bt_bf16<<<dim3(16, 32), 256, 0, stream>>>(att, wo_t, nullptr, out, 4096, 2048, 2048);
}

// Round 2
// 310.433 us; speedup vs baseline: 1.1431x; 1.1431x over previous
//
#include <hip/hip_runtime.h>
#include <hip/hip_bf16.h>
#include <cstdint>

typedef __attribute__((ext_vector_type(4))) float f32x4;
typedef __attribute__((ext_vector_type(16))) float f32x16;
typedef __attribute__((ext_vector_type(8))) short bf16x8;
typedef __attribute__((ext_vector_type(4))) unsigned int u32x4;
typedef unsigned short u16;
typedef unsigned int u32;

__device__ __forceinline__ u16 f2b(float x) {
  __hip_bfloat16 h = __float2bfloat16(x);
  return *reinterpret_cast<u16*>(&h);
}

__device__ __forceinline__ u32 pk(float a, float b) {
  return ((u32)f2b(b) << 16) | (u32)f2b(a);
}

__device__ __forceinline__ void gload16(const void* g, void* l) {
  __builtin_amdgcn_global_load_lds((const __attribute__((address_space(1))) u32*)g,
                                   (__attribute__((address_space(3))) u32*)l, 16, 0, 0);
}

// ---------------- converts ----------------

__global__ void cvt_f32_bf16(const float* __restrict__ in, u16* __restrict__ out, int n4) {
  int idx = (blockIdx.x * 256 + threadIdx.x);
  if (idx < n4) {
    const float4 v = *(const float4*)(in + (size_t)idx * 4);
    u16* o = out + (size_t)idx * 4;
    o[0] = f2b(v.x); o[1] = f2b(v.y); o[2] = f2b(v.z); o[3] = f2b(v.w);
  }
}

// out[n][k] = in[k][n] as bf16.  Three column-partitioned sources.
__global__ void w_transpose_cvt(const float* __restrict__ w0, const float* __restrict__ w1,
                                const float* __restrict__ w2, int b0, int b1,
                                int N0, int N1, int N2,
                                u16* __restrict__ out, int K) {
  __shared__ float tile[32][33];
  int k0 = blockIdx.x * 32, n0 = blockIdx.y * 32;
  const float* src; int srcN; int c0;
  if (n0 < b0)      { src = w0; srcN = N0; c0 = n0; }
  else if (n0 < b1) { src = w1; srcN = N1; c0 = n0 - b0; }
  else              { src = w2; srcN = N2; c0 = n0 - b1; }
  int tx = threadIdx.x & 31, ty = threadIdx.x >> 5;
#pragma unroll
  for (int j = 0; j < 32; j += 8)
    tile[ty + j][tx] = src[(size_t)(k0 + ty + j) * srcN + c0 + tx];
  __syncthreads();
#pragma unroll
  for (int j = 0; j < 32; j += 8)
    out[(size_t)(n0 + ty + j) * K + k0 + tx] = f2b(tile[tx][ty + j]);
}

__global__ void pack_bias(const float* __restrict__ bq, const float* __restrict__ bk,
                          const float* __restrict__ bv, float* __restrict__ out) {
  int i = blockIdx.x * 256 + threadIdx.x;
  if (i < 3072) out[i] = (i < 2048) ? bq[i] : ((i < 2560) ? bk[i - 2048] : bv[i - 2560]);
}

// V slice of qkv -> transposed bf16 (B*KVH, 128, 2048)
__global__ void v_transpose_cvt(const float* __restrict__ qkv, u16* __restrict__ vt) {
  __shared__ float tile[32][33];
  int s0 = blockIdx.x * 32;
  int d0 = blockIdx.y * 32;
  int z = blockIdx.z;              // b*4 + kvh
  int b = z >> 2, kvh = z & 3;
  int tx = threadIdx.x & 31, ty = threadIdx.x >> 5;
#pragma unroll
  for (int j = 0; j < 32; j += 8)
    tile[ty + j][tx] = qkv[((size_t)(b * 2048 + s0 + ty + j)) * 3072 + 2560 + kvh * 128 + d0 + tx];
  __syncthreads();
#pragma unroll
  for (int j = 0; j < 32; j += 8)
    vt[((size_t)z * 128 + d0 + ty + j) * 2048 + s0 + tx] = f2b(tile[tx][ty + j]);
}

// ---------------- RoPE ----------------
__global__ void rope_cvt(const float* __restrict__ qkv, u16* __restrict__ out,
                         int lognh, int col0, float scale) {
  int idx = blockIdx.x * 256 + threadIdx.x;   // pair index
  int i = idx & 63;                            // pair within head
  int nh = 1 << lognh;
  int h = (idx >> 6) & (nh - 1);
  int bs = idx >> (6 + lognh);                 // 0..4095
  int s = bs & 2047;
  int b = bs >> 11;
  const float* src = qkv + (size_t)bs * 3072 + col0 + h * 128 + 2 * i;
  float tr = src[0], ti = src[1];
  float theta = expf(-(float)i * 0.14391156831212787f);  // ln(10000)/64
  float ang = (float)s * theta;
  float sv, cv;
  sincosf(ang, &sv, &cv);
  float orr = (tr * cv - ti * sv) * scale;
  float oii = (tr * sv + ti * cv) * scale;
  u16* dst = out + (((size_t)(b * nh + h) * 2048 + s) * 128 + 2 * i);
  dst[0] = f2b(orr);
  dst[1] = f2b(oii);
}

// ---------------- GEMM (m97 structure): C = A @ Bt^T + bias ----------------
__global__ __launch_bounds__(256) void gemm_bt_bf16(
    const u16* __restrict__ A, const u16* __restrict__ Bt,
    const float* __restrict__ bias, float* __restrict__ C,
    int M, int N, int K) {
  __shared__ u16 As[128 * 32];
  __shared__ u16 Bs[128 * 32];
  const int tid = threadIdx.x;
  const int lane = tid & 63;
  const int w = tid >> 6;
  const int wr = w >> 1, wc = w & 1;
  const int m0 = blockIdx.y * 128;
  const int n0 = blockIdx.x * 128;

  f32x4 acc[4][4] = {};

  for (int k0 = 0; k0 < K; k0 += 32) {
#pragma unroll
    for (int it = 0; it < 2; ++it) {
      int c = tid + it * 256;
      int row = c >> 2;
      int off = (c & 3) * 8;
      gload16(A + (size_t)(m0 + row) * K + k0 + off, (u16*)As + w * 512 + it * 2048);
      gload16(Bt + (size_t)(n0 + row) * K + k0 + off, (u16*)Bs + w * 512 + it * 2048);
    }
    __syncthreads();
    const int col8 = (lane >> 4) * 8;
    bf16x8 a[4], bfr[4];
#pragma unroll
    for (int m = 0; m < 4; ++m)
      a[m] = *(const bf16x8*)&As[(wr * 64 + m * 16 + (lane & 15)) * 32 + col8];
#pragma unroll
    for (int n = 0; n < 4; ++n)
      bfr[n] = *(const bf16x8*)&Bs[(wc * 64 + n * 16 + (lane & 15)) * 32 + col8];
#pragma unroll
    for (int m = 0; m < 4; ++m)
#pragma unroll
      for (int n = 0; n < 4; ++n)
        acc[m][n] = __builtin_amdgcn_mfma_f32_16x16x32_bf16(a[m], bfr[n], acc[m][n], 0, 0, 0);
    __syncthreads();
  }

#pragma unroll
  for (int m = 0; m < 4; ++m) {
    int row = m0 + wr * 64 + m * 16 + ((lane >> 4) << 2);
#pragma unroll
    for (int n = 0; n < 4; ++n) {
      int col = n0 + wc * 64 + n * 16 + (lane & 15);
      float bvv = bias ? bias[col] : 0.f;
      float* cp = C + (size_t)row * N + col;
#pragma unroll
      for (int r = 0; r < 4; ++r) cp[(size_t)r * N] = acc[m][n][r] + bvv;
    }
  }
}

// ---------------- flash attention (8-wave-ladder structure, 32x32 MFMA) ----------------
// Qr: (B*H, 2048, 128) bf16, pre-scaled by 1/sqrt(128).
// Kr: (B*KVH, 2048, 128) bf16.  Vt: (B*KVH, 128, 2048) bf16.
// Att out: (B*2048, 2048) bf16 (b, s, h*128+d).
// 4 waves x 32 q-rows = 128 q/block; KV tile 64; swapped QK^T; in-register softmax.
__global__ __launch_bounds__(256) void flash_attn(
    const u16* __restrict__ Qr, const u16* __restrict__ Kr,
    const u16* __restrict__ Vt, u16* __restrict__ Att) {
  __shared__ u16 Ks[2][64 * 128];
  __shared__ u16 Vs[2][128 * 64];
  const int tid = threadIdx.x, lane = tid & 63, w = tid >> 6;
  const int lo = lane & 31, hi = lane >> 5;
  const int q0 = blockIdx.x * 128 + w * 32;
  const int h = blockIdx.y, b = blockIdx.z;
  const int kvh = h >> 2;

  const char* Khead = (const char*)(Kr + (size_t)(b * 4 + kvh) * 2048 * 128);
  const char* Vhead = (const char*)(Vt + (size_t)(b * 4 + kvh) * 128 * 2048);

  // Q fragments (B-operand of swapped QK^T): qf[ds] = Q[q0+lo][ds*16 + hi*8 .. +8]
  bf16x8 qf[8];
  {
    const u16* qp = Qr + ((size_t)(b * 16 + h) * 2048 + q0 + lo) * 128 + hi * 8;
#pragma unroll
    for (int ds = 0; ds < 8; ++ds) qf[ds] = *(const bf16x8*)(qp + ds * 16);
  }

  // per-thread staging offsets (pre-swizzled global source, linear LDS dest)
  int koff[4], voff[4];
#pragma unroll
  for (int it = 0; it < 4; ++it) {
    int c = tid + it * 256;
    int krow = c >> 4;
    koff[it] = krow * 256 + (((c & 15) * 16) ^ ((krow & 7) << 4));
    int vrow = c >> 3;
    voff[it] = vrow * 4096 + (((c & 7) * 16) ^ ((vrow & 7) << 4));
  }

#define STAGE(bufi, t)                                                \
  {                                                                   \
    _Pragma("unroll")                                                 \
    for (int it = 0; it < 4; ++it) {                                  \
      gload16(Khead + (size_t)(t) * 16384 + koff[it],                 \
              (u16*)Ks[bufi] + it * 2048 + w * 512);                  \
      gload16(Vhead + (size_t)(t) * 128 + voff[it],                   \
              (u16*)Vs[bufi] + it * 2048 + w * 512);                  \
    }                                                                 \
  }

  f32x16 o0 = {}, o1 = {}, o2 = {}, o3 = {};
  float m_run = -3.0e38f, l_run = 0.f;
  const int swz = (lane & 7) << 4;
  const int hi16 = hi * 16;

  STAGE(0, 0);
  __syncthreads();

  int buf = 0;
  for (int t = 0; t < 32; ++t) {
    if (t < 31) { STAGE(buf ^ 1, t + 1); }

    const char* Kb = (const char*)Ks[buf];
    const char* Vb = (const char*)Vs[buf];

    // QK^T (swapped: A=K rows, B=Q rows) -> lane holds S^T[key=crow(r,hi)][q=lo]
    f32x16 sc0 = {}, sc1 = {};
    __builtin_amdgcn_s_setprio(1);
#pragma unroll
    for (int ds = 0; ds < 8; ++ds) {
      bf16x8 kf = *(const bf16x8*)(Kb + lo * 256 + ((ds * 32 + hi16) ^ swz));
      sc0 = __builtin_amdgcn_mfma_f32_32x32x16_bf16(kf, qf[ds], sc0, 0, 0, 0);
    }
#pragma unroll
    for (int ds = 0; ds < 8; ++ds) {
      bf16x8 kf = *(const bf16x8*)(Kb + (32 + lo) * 256 + ((ds * 32 + hi16) ^ swz));
      sc1 = __builtin_amdgcn_mfma_f32_32x32x16_bf16(kf, qf[ds], sc1, 0, 0, 0);
    }
    __builtin_amdgcn_s_setprio(0);

    // online softmax for q-row = lo (values split across lane and lane^32)
    float pmax = sc0[0];
#pragma unroll
    for (int r = 1; r < 16; ++r) pmax = fmaxf(pmax, sc0[r]);
#pragma unroll
    for (int r = 0; r < 16; ++r) pmax = fmaxf(pmax, sc1[r]);
    pmax = fmaxf(pmax, __shfl_xor(pmax, 32, 64));

    if (!__all(pmax - m_run <= 8.0f)) {   // T13 defer-max
      float mnew = fmaxf(m_run, pmax);
      float rs = __expf(m_run - mnew);
      m_run = mnew;
      l_run *= rs;
#pragma unroll
      for (int r = 0; r < 16; ++r) {
        float rsr = __shfl(rs, (r & 3) + 8 * (r >> 2) + 4 * hi, 64);
        o0[r] *= rsr; o1[r] *= rsr; o2[r] *= rsr; o3[r] *= rsr;
      }
    }

    float lsum = 0.f;
#pragma unroll
    for (int r = 0; r < 16; ++r) { float p = __expf(sc0[r] - m_run); sc0[r] = p; lsum += p; }
#pragma unroll
    for (int r = 0; r < 16; ++r) { float p = __expf(sc1[r] - m_run); sc1[r] = p; lsum += p; }
    lsum += __shfl_xor(lsum, 32, 64);
    l_run += lsum;

    // repack P (f32, crow layout) -> PV A-fragments via bf16 pack + half-swap
#define MKPA(P, s, dst)                                               \
    {                                                                 \
      u32 a0 = pk(P[8*(s)+0], P[8*(s)+1]);                            \
      u32 a1 = pk(P[8*(s)+2], P[8*(s)+3]);                            \
      u32 b0 = pk(P[8*(s)+4], P[8*(s)+5]);                            \
      u32 b1 = pk(P[8*(s)+6], P[8*(s)+7]);                            \
      u32 t0 = hi ? a0 : b0, t1 = hi ? a1 : b1;                       \
      u32 r0 = __shfl_xor(t0, 32, 64), r1 = __shfl_xor(t1, 32, 64);   \
      u32x4 wv;                                                       \
      wv[0] = hi ? r0 : a0; wv[1] = hi ? r1 : a1;                     \
      wv[2] = hi ? b0 : r0; wv[3] = hi ? b1 : r1;                     \
      dst = __builtin_bit_cast(bf16x8, wv);                           \
    }
    bf16x8 pa0, pa1, pa2, pa3;
    MKPA(sc0, 0, pa0)
    MKPA(sc0, 1, pa1)
    MKPA(sc1, 0, pa2)
    MKPA(sc1, 1, pa3)

    // PV: A = P[32q][64k], B = V[64k][128d] (from V^T tile)
    __builtin_amdgcn_s_setprio(1);
#define PVN(on, n)                                                                                    \
    {                                                                                                 \
      const char* vrb = Vb + ((n) * 32 + lo) * 128;                                                   \
      on = __builtin_amdgcn_mfma_f32_32x32x16_bf16(pa0, *(const bf16x8*)(vrb + ((0   + hi16) ^ swz)), on, 0, 0, 0); \
      on = __builtin_amdgcn_mfma_f32_32x32x16_bf16(pa1, *(const bf16x8*)(vrb + ((32  + hi16) ^ swz)), on, 0, 0, 0); \
      on = __builtin_amdgcn_mfma_f32_32x32x16_bf16(pa2, *(const bf16x8*)(vrb + ((64  + hi16) ^ swz)), on, 0, 0, 0); \
      on = __builtin_amdgcn_mfma_f32_32x32x16_bf16(pa3, *(const bf16x8*)(vrb + ((96  + hi16) ^ swz)), on, 0, 0, 0); \
    }
    PVN(o0, 0)
    PVN(o1, 1)
    PVN(o2, 2)
    PVN(o3, 3)
    __builtin_amdgcn_s_setprio(0);

    __syncthreads();
    buf ^= 1;
  }

  // epilogue: out rows = crow(r,hi), cols = n*32 + lo
  float inv = 1.0f / l_run;
  size_t rowbase = (size_t)(b * 2048 + q0);
#pragma unroll
  for (int r = 0; r < 16; ++r) {
    int rr = (r & 3) + 8 * (r >> 2) + 4 * hi;
    float invr = __shfl(inv, rr, 64);
    u16* op = Att + (rowbase + rr) * 2048 + h * 128 + lo;
    op[0]  = f2b(o0[r] * invr);
    op[32] = f2b(o1[r] * invr);
    op[64] = f2b(o2[r] * invr);
    op[96] = f2b(o3[r] * invr);
  }
}

// ---------------- launch ----------------

extern "C" void kernel_launch(void* const* d_in, const int* in_sizes, int n_in,
                              void* d_out, int out_size, void* d_ws, size_t ws_size,
                              hipStream_t stream) {
  const float* x  = (const float*)d_in[0];
  const float* wq = (const float*)d_in[1];
  const float* bq = (const float*)d_in[2];
  const float* wk = (const float*)d_in[3];
  const float* bk = (const float*)d_in[4];
  const float* wv = (const float*)d_in[5];
  const float* bv = (const float*)d_in[6];
  const float* wo = (const float*)d_in[7];
  float* out = (float*)d_out;
  char* ws = (char*)d_ws;

  // workspace layout (bytes); att aliases x_bf (dead after QKV GEMM)
  u16*   x_bf   = (u16*)  (ws + 0);            // 16,777,216
  u16*   att    = (u16*)  (ws + 0);            // reuse after gemm1
  u16*   wqkv_t = (u16*)  (ws + 16777216);     // 12,582,912
  u16*   wo_t   = (u16*)  (ws + 29360128);     //  8,388,608
  float* biasq  = (float*)(ws + 37748736);     //     12,288
  float* qkv    = (float*)(ws + 37761024);     // 50,331,648
  u16*   q_r    = (u16*)  (ws + 88092672);     // 16,777,216
  u16*   k_r    = (u16*)  (ws + 104869888);    //  4,194,304
  u16*   v_t    = (u16*)  (ws + 109064192);    //  4,194,304  (end 113,258,496)

  // 1. converts
  cvt_f32_bf16<<<8192, 256, 0, stream>>>(x, x_bf, 2097152);
  w_transpose_cvt<<<dim3(64, 96), 256, 0, stream>>>(wq, wk, wv, 2048, 2560,
                                                    2048, 512, 512, wqkv_t, 2048);
  w_transpose_cvt<<<dim3(64, 64), 256, 0, stream>>>(wo, wo, wo, 2048, 2560,
                                                    2048, 2048, 2048, wo_t, 2048);
  pack_bias<<<12, 256, 0, stream>>>(bq, bk, bv, biasq);

  // 2. QKV projection: (4096 x 2048) @ (2048 x 3072) + bias -> fp32
  gemm_bt_bf16<<<dim3(24, 32), 256, 0, stream>>>(x_bf, wqkv_t, biasq, qkv, 4096, 3072, 2048);

  // 3. RoPE + layout (scale folded into Q); V transpose
  rope_cvt<<<16384, 256, 0, stream>>>(qkv, q_r, 4, 0, 0.08838834764831845f);
  rope_cvt<<<4096, 256, 0, stream>>>(qkv, k_r, 2, 2048, 1.0f);
  v_transpose_cvt<<<dim3(64, 4, 8), 256, 0, stream>>>(qkv, v_t);

  // 4. flash attention -> att bf16
  flash_attn<<<dim3(16, 16, 2), 256, 0, stream>>>(q_r, k_r, v_t, att);

  // 5. out projection: (4096 x 2048) @ (2048 x 2048) -> d_out fp32
  gemm_bt_bf16<<<dim3(16, 32), 256, 0, stream>>>(att, wo_t, nullptr, out, 4096, 2048, 2048);
}

// Round 4
// 294.559 us; speedup vs baseline: 1.2047x; 1.0539x over previous
//
#include <hip/hip_runtime.h>
#include <hip/hip_bf16.h>
#include <cstdint>

typedef __attribute__((ext_vector_type(4))) float f32x4;
typedef __attribute__((ext_vector_type(16))) float f32x16;
typedef __attribute__((ext_vector_type(8))) short bf16x8;
typedef __attribute__((ext_vector_type(4))) unsigned int u32x4;
typedef unsigned short u16;
typedef unsigned int u32;

__device__ __forceinline__ u16 f2b(float x) {
  __hip_bfloat16 h = __float2bfloat16(x);
  return *reinterpret_cast<u16*>(&h);
}

__device__ __forceinline__ u32 pk(float a, float b) {
  return ((u32)f2b(b) << 16) | (u32)f2b(a);
}

__device__ __forceinline__ void gload16(const void* g, void* l) {
  __builtin_amdgcn_global_load_lds((const __attribute__((address_space(1))) u32*)g,
                                   (__attribute__((address_space(3))) u32*)l, 16, 0, 0);
}

// cross-half (lane vs lane^32) reduce — HW-verified shfl_xor idiom (round 2)
__device__ __forceinline__ float xmax32(float x) {
  return fmaxf(x, __shfl_xor(x, 32, 64));
}
__device__ __forceinline__ float xsum32(float x) {
  return x + __shfl_xor(x, 32, 64);
}

// ---------------- converts ----------------

__global__ void cvt_f32_bf16(const float* __restrict__ in, u16* __restrict__ out, int n4) {
  int idx = (blockIdx.x * 256 + threadIdx.x);
  if (idx < n4) {
    const float4 v = *(const float4*)(in + (size_t)idx * 4);
    u16* o = out + (size_t)idx * 4;
    o[0] = f2b(v.x); o[1] = f2b(v.y); o[2] = f2b(v.z); o[3] = f2b(v.w);
  }
}

__global__ void w_transpose_cvt(const float* __restrict__ w0, const float* __restrict__ w1,
                                const float* __restrict__ w2, int b0, int b1,
                                int N0, int N1, int N2,
                                u16* __restrict__ out, int K) {
  __shared__ float tile[32][33];
  int k0 = blockIdx.x * 32, n0 = blockIdx.y * 32;
  const float* src; int srcN; int c0;
  if (n0 < b0)      { src = w0; srcN = N0; c0 = n0; }
  else if (n0 < b1) { src = w1; srcN = N1; c0 = n0 - b0; }
  else              { src = w2; srcN = N2; c0 = n0 - b1; }
  int tx = threadIdx.x & 31, ty = threadIdx.x >> 5;
#pragma unroll
  for (int j = 0; j < 32; j += 8)
    tile[ty + j][tx] = src[(size_t)(k0 + ty + j) * srcN + c0 + tx];
  __syncthreads();
#pragma unroll
  for (int j = 0; j < 32; j += 8)
    out[(size_t)(n0 + ty + j) * K + k0 + tx] = f2b(tile[tx][ty + j]);
}

__global__ void pack_bias(const float* __restrict__ bq, const float* __restrict__ bk,
                          const float* __restrict__ bv, float* __restrict__ out) {
  int i = blockIdx.x * 256 + threadIdx.x;
  if (i < 3072) out[i] = (i < 2048) ? bq[i] : ((i < 2560) ? bk[i - 2048] : bv[i - 2560]);
}

__global__ void v_transpose_cvt(const float* __restrict__ qkv, u16* __restrict__ vt) {
  __shared__ float tile[32][33];
  int s0 = blockIdx.x * 32;
  int d0 = blockIdx.y * 32;
  int z = blockIdx.z;              // b*4 + kvh
  int b = z >> 2, kvh = z & 3;
  int tx = threadIdx.x & 31, ty = threadIdx.x >> 5;
#pragma unroll
  for (int j = 0; j < 32; j += 8)
    tile[ty + j][tx] = qkv[((size_t)(b * 2048 + s0 + ty + j)) * 3072 + 2560 + kvh * 128 + d0 + tx];
  __syncthreads();
#pragma unroll
  for (int j = 0; j < 32; j += 8)
    vt[((size_t)z * 128 + d0 + ty + j) * 2048 + s0 + tx] = f2b(tile[tx][ty + j]);
}

// ---------------- RoPE ----------------
__global__ void rope_cvt(const float* __restrict__ qkv, u16* __restrict__ out,
                         int lognh, int col0, float scale) {
  int idx = blockIdx.x * 256 + threadIdx.x;   // pair index
  int i = idx & 63;                            // pair within head
  int nh = 1 << lognh;
  int h = (idx >> 6) & (nh - 1);
  int bs = idx >> (6 + lognh);                 // 0..4095
  int s = bs & 2047;
  int b = bs >> 11;
  const float* src = qkv + (size_t)bs * 3072 + col0 + h * 128 + 2 * i;
  float tr = src[0], ti = src[1];
  float theta = expf(-(float)i * 0.14391156831212787f);  // ln(10000)/64
  float ang = (float)s * theta;
  float sv, cv;
  sincosf(ang, &sv, &cv);
  float orr = (tr * cv - ti * sv) * scale;
  float oii = (tr * sv + ti * cv) * scale;
  u16* dst = out + (((size_t)(b * nh + h) * 2048 + s) * 128 + 2 * i);
  dst[0] = f2b(orr);
  dst[1] = f2b(oii);
}

// ---------------- GEMM (m97 structure): C = A @ Bt^T + bias ----------------
__global__ __launch_bounds__(256) void gemm_bt_bf16(
    const u16* __restrict__ A, const u16* __restrict__ Bt,
    const float* __restrict__ bias, float* __restrict__ C,
    int M, int N, int K) {
  __shared__ u16 As[128 * 32];
  __shared__ u16 Bs[128 * 32];
  const int tid = threadIdx.x;
  const int lane = tid & 63;
  const int w = tid >> 6;
  const int wr = w >> 1, wc = w & 1;
  const int m0 = blockIdx.y * 128;
  const int n0 = blockIdx.x * 128;

  f32x4 acc[4][4] = {};

  for (int k0 = 0; k0 < K; k0 += 32) {
#pragma unroll
    for (int it = 0; it < 2; ++it) {
      int c = tid + it * 256;
      int row = c >> 2;
      int off = (c & 3) * 8;
      gload16(A + (size_t)(m0 + row) * K + k0 + off, (u16*)As + w * 512 + it * 2048);
      gload16(Bt + (size_t)(n0 + row) * K + k0 + off, (u16*)Bs + w * 512 + it * 2048);
    }
    __syncthreads();
    const int col8 = (lane >> 4) * 8;
    bf16x8 a[4], bfr[4];
#pragma unroll
    for (int m = 0; m < 4; ++m)
      a[m] = *(const bf16x8*)&As[(wr * 64 + m * 16 + (lane & 15)) * 32 + col8];
#pragma unroll
    for (int n = 0; n < 4; ++n)
      bfr[n] = *(const bf16x8*)&Bs[(wc * 64 + n * 16 + (lane & 15)) * 32 + col8];
#pragma unroll
    for (int m = 0; m < 4; ++m)
#pragma unroll
      for (int n = 0; n < 4; ++n)
        acc[m][n] = __builtin_amdgcn_mfma_f32_16x16x32_bf16(a[m], bfr[n], acc[m][n], 0, 0, 0);
    __syncthreads();
  }

#pragma unroll
  for (int m = 0; m < 4; ++m) {
    int row = m0 + wr * 64 + m * 16 + ((lane >> 4) << 2);
#pragma unroll
    for (int n = 0; n < 4; ++n) {
      int col = n0 + wc * 64 + n * 16 + (lane & 15);
      float bvv = bias ? bias[col] : 0.f;
      float* cp = C + (size_t)row * N + col;
#pragma unroll
      for (int r = 0; r < 4; ++r) cp[(size_t)r * N] = acc[m][n][r] + bvv;
    }
  }
}

// ---------------- flash attention v4 ----------------
// Qr: (B*H, 2048, 128) bf16 pre-scaled by 1/sqrt(128).
// Kr: (B*KVH, 2048, 128) bf16.  Vt: (B*KVH, 128, 2048) bf16.
// Att out: (B*2048, 2048) bf16.
// 2 waves x 32 q-rows = 64 q/block; KVBLK=32, double-buffered 32KB LDS;
// swapped QK^T (32x32 mfma), in-register softmax, shfl_xor repack (HW-verified).
__global__ __launch_bounds__(128, 3) void flash_attn(
    const u16* __restrict__ Qr, const u16* __restrict__ Kr,
    const u16* __restrict__ Vt, u16* __restrict__ Att) {
  __shared__ u16 Ks[2][32 * 128];   // 8KB/buf: 32 rows x 256B, slot ^= row&7
  __shared__ u16 Vs[2][128 * 32];   // 8KB/buf: 128 rows x 64B, slot ^= (row>>1)&3
  const int tid = threadIdx.x, lane = tid & 63, w = tid >> 6;
  const int lo = lane & 31, hi = lane >> 5;
  const int q0 = blockIdx.x * 64 + w * 32;
  const int h = blockIdx.y, b = blockIdx.z;
  const int kvh = h >> 2;

  const char* Khead = (const char*)(Kr + (size_t)(b * 4 + kvh) * 2048 * 128);
  const char* Vhead = (const char*)(Vt + (size_t)(b * 4 + kvh) * 128 * 2048);

  // Q fragments (B-operand of swapped QK^T)
  bf16x8 qf[8];
  {
    const u16* qp = Qr + ((size_t)(b * 16 + h) * 2048 + q0 + lo) * 128 + hi * 8;
#pragma unroll
    for (int ds = 0; ds < 8; ++ds) qf[ds] = *(const bf16x8*)(qp + ds * 16);
  }

  // staging: per instr it (0..3), flat slot c = it*128 + tid covers the 8KB tile.
  // global source pre-swizzled, LDS dest linear (rule 21).
#define STAGE(bufi, t)                                                        \
  {                                                                           \
    _Pragma("unroll")                                                         \
    for (int it = 0; it < 4; ++it) {                                          \
      int c = it * 128 + tid;                                                 \
      int krow = c >> 4;                                                      \
      int koff = krow * 256 + ((c & 15) << 4 ^ ((krow & 7) << 4));            \
      gload16(Khead + (size_t)(t) * 8192 + koff,                              \
              (u16*)Ks[bufi] + it * 1024 + w * 512);                          \
      int vrow = c >> 2;                                                      \
      int voff = vrow * 4096 + ((c & 3) << 4 ^ (((vrow >> 1) & 3) << 4));     \
      gload16(Vhead + (size_t)(t) * 64 + voff,                                \
              (u16*)Vs[bufi] + it * 1024 + w * 512);                          \
    }                                                                         \
  }

  f32x16 o0 = {}, o1 = {}, o2 = {}, o3 = {};
  float m_run = -3.0e38f, l_run = 0.f;
  const int swz = (lo & 7) << 4;
  const int vswz = ((lo >> 1) & 3) << 4;
  const int hi16 = hi * 16;

  STAGE(0, 0);
  __syncthreads();

  int buf = 0;
  for (int t = 0; t < 64; ++t) {
    int tn = (t < 63) ? t + 1 : 63;
    STAGE(buf ^ 1, tn);

    const char* Kb = (const char*)Ks[buf];
    const char* Vb = (const char*)Vs[buf];

    // QK^T (swapped): lane holds S^T[key=crow(r,hi)][q=lo], keys 0..31 of tile
    f32x16 sc = {};
    __builtin_amdgcn_s_setprio(1);
#pragma unroll
    for (int ds = 0; ds < 8; ++ds) {
      bf16x8 kf = *(const bf16x8*)(Kb + lo * 256 + ((ds * 32 + hi16) ^ swz));
      sc = __builtin_amdgcn_mfma_f32_32x32x16_bf16(kf, qf[ds], sc, 0, 0, 0);
    }
    __builtin_amdgcn_s_setprio(0);

    // online softmax for q-row=lo (split across lane / lane^32): tree max
    float m01 = fmaxf(fmaxf(sc[0], sc[1]), fmaxf(sc[2], sc[3]));
    float m23 = fmaxf(fmaxf(sc[4], sc[5]), fmaxf(sc[6], sc[7]));
    float m45 = fmaxf(fmaxf(sc[8], sc[9]), fmaxf(sc[10], sc[11]));
    float m67 = fmaxf(fmaxf(sc[12], sc[13]), fmaxf(sc[14], sc[15]));
    float pmax = xmax32(fmaxf(fmaxf(m01, m23), fmaxf(m45, m67)));

    if (!__all(pmax - m_run <= 8.0f)) {   // T13 defer-max
      float mnew = fmaxf(m_run, pmax);
      float rs = __expf(m_run - mnew);
      m_run = mnew;
      l_run *= rs;
#pragma unroll
      for (int r = 0; r < 16; ++r) {
        float rsr = __shfl(rs, (r & 3) + 8 * (r >> 2) + 4 * hi, 64);
        o0[r] *= rsr; o1[r] *= rsr; o2[r] *= rsr; o3[r] *= rsr;
      }
    }

    float lsum = 0.f;
#pragma unroll
    for (int r = 0; r < 16; ++r) { float p = __expf(sc[r] - m_run); sc[r] = p; lsum += p; }
    l_run += xsum32(lsum);

    // repack P -> PV A-fragments via shfl_xor half-swap (round-2 HW-verified)
    bf16x8 pa0, pa1;
    {
      u32 a0 = pk(sc[0], sc[1]),   a1 = pk(sc[2], sc[3]);
      u32 b0 = pk(sc[4], sc[5]),   b1 = pk(sc[6], sc[7]);
      u32 t0 = hi ? a0 : b0, t1 = hi ? a1 : b1;
      u32 r0 = __shfl_xor(t0, 32, 64), r1 = __shfl_xor(t1, 32, 64);
      u32x4 w0;
      w0[0] = hi ? r0 : a0; w0[1] = hi ? r1 : a1;
      w0[2] = hi ? b0 : r0; w0[3] = hi ? b1 : r1;
      pa0 = __builtin_bit_cast(bf16x8, w0);
      u32 c0 = pk(sc[8], sc[9]),   c1 = pk(sc[10], sc[11]);
      u32 d0 = pk(sc[12], sc[13]), d1 = pk(sc[14], sc[15]);
      u32 t2 = hi ? c0 : d0, t3 = hi ? c1 : d1;
      u32 r2 = __shfl_xor(t2, 32, 64), r3 = __shfl_xor(t3, 32, 64);
      u32x4 w1;
      w1[0] = hi ? r2 : c0; w1[1] = hi ? r3 : c1;
      w1[2] = hi ? d0 : r2; w1[3] = hi ? d1 : r3;
      pa1 = __builtin_bit_cast(bf16x8, w1);
    }

    // PV: A = P[32q][32k], B = V[32k][128d] (from V^T tile, 64B rows)
    __builtin_amdgcn_s_setprio(1);
#define PVN(on, n)                                                                                     \
    {                                                                                                  \
      const char* vrb = Vb + ((n) * 32 + lo) * 64;                                                     \
      on = __builtin_amdgcn_mfma_f32_32x32x16_bf16(pa0, *(const bf16x8*)(vrb + ((0  + hi16) ^ vswz)), on, 0, 0, 0); \
      on = __builtin_amdgcn_mfma_f32_32x32x16_bf16(pa1, *(const bf16x8*)(vrb + ((32 + hi16) ^ vswz)), on, 0, 0, 0); \
    }
    PVN(o0, 0)
    PVN(o1, 1)
    PVN(o2, 2)
    PVN(o3, 3)
    __builtin_amdgcn_s_setprio(0);

    __syncthreads();
    buf ^= 1;
  }

  // epilogue: out rows = crow(r,hi), cols = n*32 + lo
  float inv = 1.0f / l_run;
  size_t rowbase = (size_t)(b * 2048 + q0);
#pragma unroll
  for (int r = 0; r < 16; ++r) {
    int rr = (r & 3) + 8 * (r >> 2) + 4 * hi;
    float invr = __shfl(inv, rr, 64);
    u16* op = Att + (rowbase + rr) * 2048 + h * 128 + lo;
    op[0]  = f2b(o0[r] * invr);
    op[32] = f2b(o1[r] * invr);
    op[64] = f2b(o2[r] * invr);
    op[96] = f2b(o3[r] * invr);
  }
}

// ---------------- launch ----------------

extern "C" void kernel_launch(void* const* d_in, const int* in_sizes, int n_in,
                              void* d_out, int out_size, void* d_ws, size_t ws_size,
                              hipStream_t stream) {
  const float* x  = (const float*)d_in[0];
  const float* wq = (const float*)d_in[1];
  const float* bq = (const float*)d_in[2];
  const float* wk = (const float*)d_in[3];
  const float* bk = (const float*)d_in[4];
  const float* wv = (const float*)d_in[5];
  const float* bv = (const float*)d_in[6];
  const float* wo = (const float*)d_in[7];
  float* out = (float*)d_out;
  char* ws = (char*)d_ws;

  // workspace layout (bytes); att aliases x_bf (dead after QKV GEMM)
  u16*   x_bf   = (u16*)  (ws + 0);            // 16,777,216
  u16*   att    = (u16*)  (ws + 0);            // reuse after gemm1
  u16*   wqkv_t = (u16*)  (ws + 16777216);     // 12,582,912
  u16*   wo_t   = (u16*)  (ws + 29360128);     //  8,388,608
  float* biasq  = (float*)(ws + 37748736);     //     12,288
  float* qkv    = (float*)(ws + 37761024);     // 50,331,648
  u16*   q_r    = (u16*)  (ws + 88092672);     // 16,777,216
  u16*   k_r    = (u16*)  (ws + 104869888);    //  4,194,304
  u16*   v_t    = (u16*)  (ws + 109064192);    //  4,194,304  (end 113,258,496)

  // 1. converts
  cvt_f32_bf16<<<8192, 256, 0, stream>>>(x, x_bf, 2097152);
  w_transpose_cvt<<<dim3(64, 96), 256, 0, stream>>>(wq, wk, wv, 2048, 2560,
                                                    2048, 512, 512, wqkv_t, 2048);
  w_transpose_cvt<<<dim3(64, 64), 256, 0, stream>>>(wo, wo, wo, 2048, 2560,
                                                    2048, 2048, 2048, wo_t, 2048);
  pack_bias<<<12, 256, 0, stream>>>(bq, bk, bv, biasq);

  // 2. QKV projection: (4096 x 2048) @ (2048 x 3072) + bias -> fp32
  gemm_bt_bf16<<<dim3(24, 32), 256, 0, stream>>>(x_bf, wqkv_t, biasq, qkv, 4096, 3072, 2048);

  // 3. RoPE + layout (scale folded into Q); V transpose
  rope_cvt<<<16384, 256, 0, stream>>>(qkv, q_r, 4, 0, 0.08838834764831845f);
  rope_cvt<<<4096, 256, 0, stream>>>(qkv, k_r, 2, 2048, 1.0f);
  v_transpose_cvt<<<dim3(64, 4, 8), 256, 0, stream>>>(qkv, v_t);

  // 4. flash attention -> att bf16
  flash_attn<<<dim3(32, 16, 2), 128, 0, stream>>>(q_r, k_r, v_t, att);

  // 5. out projection: (4096 x 2048) @ (2048 x 2048) -> d_out fp32
  gemm_bt_bf16<<<dim3(16, 32), 256, 0, stream>>>(att, wo_t, nullptr, out, 4096, 2048, 2048);
}